// Round 3
// baseline (1094.376 us; speedup 1.0000x reference)
//
#include <hip/hip_runtime.h>
#include <cstdint>
#include <cstddef>

// ---------------------------------------------------------------------------
// HiERABlock, MI355X.  Dtype-adaptive: a detector kernel sniffs whether the
// inputs are fp32 or bf16 (flag in d_ws, branched on by input-touching
// kernels only — graph-safe, data-dependent).  Internal pipeline all bf16,
// "windowed row order": row = win*196 + n, win = b*16+hb*4+wb, n = i*14+j.
// GEMMs: A (MxK) bf16 row-major x BT (NxK) bf16 row-major, MFMA 16x16x32,
// m97-style global_load_lds staging.  Middle section chunked to fit ws_size.
// ---------------------------------------------------------------------------

typedef unsigned short u16;
typedef short short8 __attribute__((ext_vector_type(8)));
typedef float floatx4 __attribute__((ext_vector_type(4)));

static __device__ __forceinline__ float bf2f(u16 u) {
  return __uint_as_float(((unsigned)u) << 16);
}
static __device__ __forceinline__ u16 f2bf(float f) {
  unsigned u = __float_as_uint(f);
  return (u16)((u + 0x7FFFu + ((u >> 16) & 1u)) >> 16);
}
static __device__ __forceinline__ float ldin(const void* p, size_t i, int isf) {
  return isf ? ((const float*)p)[i] : bf2f(((const u16*)p)[i]);
}
static __device__ __forceinline__ void gload_lds16(const void* g, void* l) {
  __builtin_amdgcn_global_load_lds(
      (const __attribute__((address_space(1))) void*)g,
      (__attribute__((address_space(3))) void*)l, 16, 0, 0);
}

// ---- dtype detector: bf16-interpret first 4096 u16 of x; count huge exps ---
__global__ __launch_bounds__(256) void detect_kernel(const u16* __restrict__ x,
                                                     int* __restrict__ flag) {
  __shared__ int tot;
  if (threadIdx.x == 0) tot = 0;
  __syncthreads();
  int cnt = 0;
  for (int i = threadIdx.x; i < 4096; i += 256) {
    int e = (x[i] >> 7) & 0xFF;
    if (e >= 0xC1) cnt++;   // |v| >= 2^66: impossible for N(0,1) bf16 data
  }
  atomicAdd(&tot, cnt);
  __syncthreads();
  if (threadIdx.x == 0) flag[0] = (tot > 16) ? 1 : 0;
}

// ---- convert all small params to bf16 into P (20268 u16) -------------------
// layout: n1w 0 | n1b 768 | qkv_b 1536 | proj_b 3840 | n2w 4608 | n2b 5376 |
//         fc1_b 6144 | fc2_b 9216 | g1 9984 | g2 10752 | btab 11520 (+8748)
__global__ __launch_bounds__(256) void cvt_params_kernel(
    const void* n1w, const void* n1b, const void* qkvb, const void* projb,
    const void* n2w, const void* n2b, const void* fc1b, const void* fc2b,
    const void* g1, const void* g2, const void* bt, u16* __restrict__ P,
    const int* __restrict__ flag) {
  int isf = *flag;
  int i = blockIdx.x * 256 + threadIdx.x;
  const void* src; int off;
  if      (i < 768)   { src = n1w;   off = i; }
  else if (i < 1536)  { src = n1b;   off = i - 768; }
  else if (i < 3840)  { src = qkvb;  off = i - 1536; }
  else if (i < 4608)  { src = projb; off = i - 3840; }
  else if (i < 5376)  { src = n2w;   off = i - 4608; }
  else if (i < 6144)  { src = n2b;   off = i - 5376; }
  else if (i < 9216)  { src = fc1b;  off = i - 6144; }
  else if (i < 9984)  { src = fc2b;  off = i - 9216; }
  else if (i < 10752) { src = g1;    off = i - 9984; }
  else if (i < 11520) { src = g2;    off = i - 10752; }
  else if (i < 20268) { src = bt;    off = i - 11520; }
  else return;
  P[i] = f2bf(ldin(src, off, isf));
}

// ---- weight transpose: W (K x N) fp32/bf16 -> WT (N x K) bf16 --------------
__global__ __launch_bounds__(256) void wtr_kernel(const void* __restrict__ W,
                                                  u16* __restrict__ WT,
                                                  int K, int N,
                                                  const int* __restrict__ flag) {
  int isf = *flag;
  __shared__ u16 tl[32][33];
  int tx = threadIdx.x, ty = threadIdx.y;
  int n0 = blockIdx.x * 32, k0 = blockIdx.y * 32;
#pragma unroll
  for (int j = 0; j < 32; j += 8)
    tl[ty + j][tx] = f2bf(ldin(W, (size_t)(k0 + ty + j) * N + n0 + tx, isf));
  __syncthreads();
#pragma unroll
  for (int j = 0; j < 32; j += 8)
    WT[(size_t)(n0 + ty + j) * K + k0 + tx] = tl[tx][ty + j];
}

// ---- input permute: x (8,768,56,56) -> shortcut windowed (25088,768) bf16 --
__global__ __launch_bounds__(256) void tin_kernel(const void* __restrict__ x,
                                                  u16* __restrict__ sc,
                                                  const int* __restrict__ flag) {
  int isf = *flag;
  int cc = blockIdx.x, h = blockIdx.y, b = blockIdx.z;  // grid (12,56,8)
  __shared__ u16 tile[64 * 57];
  int tid = threadIdx.x;
  for (int i = tid; i < 64 * 56; i += 256) {
    int ci = i / 56, w = i - ci * 56;
    tile[ci * 57 + w] =
        f2bf(ldin(x, (((size_t)b * 768 + cc * 64 + ci) * 56 + h) * 56 + w, isf));
  }
  __syncthreads();
  int hb = h / 14, hi = h - hb * 14;
  for (int i = tid; i < 56 * 64; i += 256) {
    int w = i >> 6, ci = i & 63;
    int wb = w / 14, wj = w - wb * 14;
    int r = (b * 16 + hb * 4 + wb) * 196 + hi * 14 + wj;
    sc[(size_t)r * 768 + cc * 64 + ci] = tile[ci * 57 + w];
  }
}

// ---- output permute: xs bf16 windowed -> out (8,768,56,56) fp32/bf16 -------
__global__ __launch_bounds__(256) void tout_kernel(const u16* __restrict__ src,
                                                   void* __restrict__ out,
                                                   const int* __restrict__ flag) {
  int isf = *flag;
  int cc = blockIdx.x, h = blockIdx.y, b = blockIdx.z;
  __shared__ u16 tile[64 * 57];
  int tid = threadIdx.x;
  int hb = h / 14, hi = h - hb * 14;
  for (int i = tid; i < 56 * 64; i += 256) {
    int w = i >> 6, ci = i & 63;
    int wb = w / 14, wj = w - wb * 14;
    int r = (b * 16 + hb * 4 + wb) * 196 + hi * 14 + wj;
    tile[ci * 57 + w] = src[(size_t)r * 768 + cc * 64 + ci];
  }
  __syncthreads();
  for (int i = tid; i < 64 * 56; i += 256) {
    int ci = i / 56, w = i - ci * 56;
    size_t o = (((size_t)b * 768 + cc * 64 + ci) * 56 + h) * 56 + w;
    if (isf) ((float*)out)[o] = bf2f(tile[ci * 57 + w]);
    else     ((u16*)out)[o]   = tile[ci * 57 + w];
  }
}

// ---- LayerNorm over C=768 (bf16 in/out), one block per row -----------------
__global__ __launch_bounds__(256) void ln_kernel(const u16* __restrict__ xin,
                                                 const u16* __restrict__ wt,
                                                 const u16* __restrict__ bs,
                                                 u16* __restrict__ out) {
  int row = blockIdx.x, t = threadIdx.x;
  const u16* xr = xin + (size_t)row * 768;
  float v0 = bf2f(xr[t]), v1 = bf2f(xr[t + 256]), v2 = bf2f(xr[t + 512]);
  float s1 = v0 + v1 + v2;
  float s2 = v0 * v0 + v1 * v1 + v2 * v2;
#pragma unroll
  for (int off = 32; off > 0; off >>= 1) {
    s1 += __shfl_xor(s1, off);
    s2 += __shfl_xor(s2, off);
  }
  __shared__ float p1[4], p2[4];
  if ((t & 63) == 0) { p1[t >> 6] = s1; p2[t >> 6] = s2; }
  __syncthreads();
  float S1 = p1[0] + p1[1] + p1[2] + p1[3];
  float S2 = p2[0] + p2[1] + p2[2] + p2[3];
  float mu = S1 * (1.f / 768.f);
  float var = S2 * (1.f / 768.f) - mu * mu;
  float rs = rsqrtf(var + 1e-5f);
  u16* orow = out + (size_t)row * 768;
  orow[t]       = f2bf((v0 - mu) * rs * bf2f(wt[t])       + bf2f(bs[t]));
  orow[t + 256] = f2bf((v1 - mu) * rs * bf2f(wt[t + 256]) + bf2f(bs[t + 256]));
  orow[t + 512] = f2bf((v2 - mu) * rs * bf2f(wt[t + 512]) + bf2f(bs[t + 512]));
}

// ---- GEMM: C = A(MxK) * BT(NxK)^T + bias, fused epilogues ------------------
// EPI 0: out = bf16(v).  EPI 1: out = bf16(bf2f(out) + gamma*v) (in-place
// layerscale residual).  EPI 2: out = bf16(gelu(v)).
template <int EPI>
__global__ __launch_bounds__(256) void gemm_kernel(
    const u16* __restrict__ A, const u16* __restrict__ BT,
    const u16* __restrict__ bias, const u16* __restrict__ gamma,
    u16* out, int N, int K) {
  __shared__ u16 As[128 * 32];
  __shared__ u16 Bs[128 * 32];
  int tid = threadIdx.x;
  int w = tid >> 6, l = tid & 63;
  int lane15 = l & 15, quad = l >> 4;
  int m0 = blockIdx.y * 128, n0 = blockIdx.x * 128;
  int wm = w & 1, wn = w >> 1;
  floatx4 acc[4][4];
#pragma unroll
  for (int i = 0; i < 4; i++)
#pragma unroll
    for (int j = 0; j < 4; j++)
#pragma unroll
      for (int e = 0; e < 4; e++) acc[i][j][e] = 0.f;

  const u16* Abase = A + (size_t)m0 * K;
  const u16* Bbase = BT + (size_t)n0 * K;
  int rseg = l >> 2, ch = l & 3;

  for (int kt = 0; kt < K; kt += 32) {
    __syncthreads();
#pragma unroll
    for (int sI = 0; sI < 2; ++sI) {
      int s = w * 2 + sI;
      gload_lds16(Abase + (size_t)(s * 16 + rseg) * K + kt + ch * 8, &As[s * 512]);
      gload_lds16(Bbase + (size_t)(s * 16 + rseg) * K + kt + ch * 8, &Bs[s * 512]);
    }
    __syncthreads();
    short8 af[4], bf[4];
#pragma unroll
    for (int mi = 0; mi < 4; ++mi)
      af[mi] = *(const short8*)&As[(wm * 64 + mi * 16 + lane15) * 32 + quad * 8];
#pragma unroll
    for (int ni = 0; ni < 4; ++ni)
      bf[ni] = *(const short8*)&Bs[(wn * 64 + ni * 16 + lane15) * 32 + quad * 8];
#pragma unroll
    for (int mi = 0; mi < 4; ++mi)
#pragma unroll
      for (int ni = 0; ni < 4; ++ni)
        acc[mi][ni] = __builtin_amdgcn_mfma_f32_16x16x32_bf16(
            af[mi], bf[ni], acc[mi][ni], 0, 0, 0);
  }

#pragma unroll
  for (int mi = 0; mi < 4; ++mi) {
    int row0 = m0 + wm * 64 + mi * 16 + quad * 4;
#pragma unroll
    for (int ni = 0; ni < 4; ++ni) {
      int col = n0 + wn * 64 + ni * 16 + lane15;
      float bv = bf2f(bias[col]);
#pragma unroll
      for (int reg = 0; reg < 4; ++reg) {
        int row = row0 + reg;
        float v = acc[mi][ni][reg] + bv;
        size_t idx = (size_t)row * N + col;
        if (EPI == 0) {
          out[idx] = f2bf(v);
        } else if (EPI == 1) {
          out[idx] = f2bf(bf2f(out[idx]) + bf2f(gamma[col]) * v);
        } else {
          out[idx] = f2bf(0.5f * v * (1.f + erff(v * 0.70710678118f)));
        }
      }
    }
  }
}

// ---- window attention: one block per (window, head). LDS ~36.7 KB ----------
__global__ __launch_bounds__(256) void attn_kernel(const u16* __restrict__ qkv,
                                                   const u16* __restrict__ btab,
                                                   u16* __restrict__ out) {
  __shared__ __align__(16) u16 VT[64 * 232];    // cols 196..223 zeroed
  __shared__ __align__(16) u16 Pa[4 * 16 * 32]; // per-wave P chunks
  __shared__ float bS[729];
  int bid = blockIdx.x;
  int win = bid / 12, h = bid - win * 12;
  int tid = threadIdx.x, w = tid >> 6, l = tid & 63;
  int lane15 = l & 15, quad = l >> 4;
  const u16* qbase = qkv + (size_t)win * 196 * 2304;

  for (int i = tid; i < 64 * 28; i += 256) {
    int d = i / 28, m = i - d * 28;
    VT[d * 232 + 196 + m] = 0;
  }
  for (int i = tid; i < 196 * 64; i += 256) {
    int m = i >> 6, d = i & 63;
    VT[d * 232 + m] = qbase[(size_t)m * 2304 + 1536 + h * 64 + d];
  }
  for (int i = tid; i < 729; i += 256) bS[i] = bf2f(btab[i * 12 + h]);
  __syncthreads();

  u16* Pw = Pa + w * 512;
  for (int rt = w; rt < 13; rt += 4) {
    floatx4 acc[13];
#pragma unroll
    for (int nt = 0; nt < 13; ++nt)
#pragma unroll
      for (int e = 0; e < 4; ++e) acc[nt][e] = 0.f;

    int rq = rt * 16 + lane15;
    bool qok = rq < 196;
#pragma unroll
    for (int kk = 0; kk < 2; ++kk) {
      short8 qf;
      if (qok)
        qf = *(const short8*)&qbase[(size_t)rq * 2304 + h * 64 + kk * 32 + quad * 8];
      else
#pragma unroll
        for (int e = 0; e < 8; ++e) qf[e] = 0;
#pragma unroll
      for (int nt = 0; nt < 13; ++nt) {
        int n = nt * 16 + lane15;  // rows 196..207 over-read (allocated, masked)
        short8 kf = *(const short8*)&qbase[(size_t)n * 2304 + 768 + h * 64 + kk * 32 + quad * 8];
        acc[nt] = __builtin_amdgcn_mfma_f32_16x16x32_bf16(qf, kf, acc[nt], 0, 0, 0);
      }
    }

    int i1[4], j1[4]; bool rv[4]; float mx[4], sm[4];
#pragma unroll
    for (int reg = 0; reg < 4; ++reg) {
      int r = rt * 16 + quad * 4 + reg;
      i1[reg] = r / 14; j1[reg] = r - i1[reg] * 14;
      rv[reg] = r < 196; mx[reg] = -1e30f; sm[reg] = 0.f;
    }
#pragma unroll
    for (int nt = 0; nt < 13; ++nt) {
      int cc = nt * 16 + lane15;
      bool cv = cc < 196;
      int i2 = cc / 14, j2 = cc - i2 * 14;
#pragma unroll
      for (int reg = 0; reg < 4; ++reg) {
        float v;
        if (cv) {
          v = acc[nt][reg] * 0.125f;
          if (rv[reg]) v += bS[(i1[reg] - i2 + 13) * 27 + (j1[reg] - j2 + 13)];
        } else v = -1e30f;
        acc[nt][reg] = v;
        mx[reg] = fmaxf(mx[reg], v);
      }
    }
#pragma unroll
    for (int reg = 0; reg < 4; ++reg)
#pragma unroll
      for (int off = 1; off < 16; off <<= 1)
        mx[reg] = fmaxf(mx[reg], __shfl_xor(mx[reg], off));
#pragma unroll
    for (int nt = 0; nt < 13; ++nt)
#pragma unroll
      for (int reg = 0; reg < 4; ++reg) {
        float p = __expf(acc[nt][reg] - mx[reg]);
        acc[nt][reg] = p; sm[reg] += p;
      }
#pragma unroll
    for (int reg = 0; reg < 4; ++reg) {
#pragma unroll
      for (int off = 1; off < 16; off <<= 1) sm[reg] += __shfl_xor(sm[reg], off);
      sm[reg] = 1.f / sm[reg];
    }

    floatx4 oa[4];
#pragma unroll
    for (int dt = 0; dt < 4; ++dt)
#pragma unroll
      for (int e = 0; e < 4; ++e) oa[dt][e] = 0.f;
#pragma unroll
    for (int kk = 0; kk < 7; ++kk) {
#pragma unroll
      for (int p = 0; p < 2; ++p) {
        int nt = kk * 2 + p;
#pragma unroll
        for (int reg = 0; reg < 4; ++reg) {
          float v = (nt < 13) ? acc[nt][reg] * sm[reg] : 0.f;
          Pw[(quad * 4 + reg) * 32 + p * 16 + lane15] = f2bf(v);
        }
      }
      asm volatile("s_waitcnt lgkmcnt(0)" ::: "memory");
      short8 pf = *(const short8*)&Pw[lane15 * 32 + quad * 8];
#pragma unroll
      for (int dt = 0; dt < 4; ++dt) {
        short8 vf = *(const short8*)&VT[(dt * 16 + lane15) * 232 + kk * 32 + quad * 8];
        oa[dt] = __builtin_amdgcn_mfma_f32_16x16x32_bf16(pf, vf, oa[dt], 0, 0, 0);
      }
      asm volatile("s_waitcnt lgkmcnt(0)" ::: "memory");
    }
#pragma unroll
    for (int dt = 0; dt < 4; ++dt)
#pragma unroll
      for (int reg = 0; reg < 4; ++reg) {
        int r = rt * 16 + quad * 4 + reg;
        if (r < 196)
          out[((size_t)win * 196 + r) * 768 + h * 64 + dt * 16 + lane15] =
              f2bf(oa[dt][reg]);
      }
  }
}

// ---------------------------------------------------------------------------
extern "C" void kernel_launch(void* const* d_in, const int* in_sizes, int n_in,
                              void* d_out, int out_size, void* d_ws, size_t ws_size,
                              hipStream_t stream) {
  const void* x      = d_in[0];
  const void* n1w    = d_in[1];
  const void* n1b    = d_in[2];
  const void* qkv_w  = d_in[3];
  const void* qkv_b  = d_in[4];
  const void* btab   = d_in[5];
  const void* proj_w = d_in[6];
  const void* proj_b = d_in[7];
  const void* n2w    = d_in[8];
  const void* n2b    = d_in[9];
  const void* fc1_w  = d_in[10];
  const void* fc1_b  = d_in[11];
  const void* fc2_w  = d_in[12];
  const void* fc2_b  = d_in[13];
  const void* gamma1 = d_in[14];
  const void* gamma2 = d_in[15];
  (void)in_sizes; (void)n_in; (void)out_size;

  // chunk count from ws_size (constant across calls -> graph-safe)
  int c;
  if      (ws_size >= 245432576ull) c = 1;
  else if (ws_size >= 168362240ull) c = 2;
  else                              c = 4;   // needs 129,827,072 B
  const int R = 25088 / c;
  const int WN = 128 / c;

  char* ws = (char*)d_ws;
  int*  flag  = (int*)ws;                     // 256 B
  u16*  P     = (u16*)(ws + 256);             // params, 64 KB region
  u16*  qkvT  = (u16*)(ws + 65792);           // 3,538,944
  u16*  projT = (u16*)(ws + 65792 + 3538944); // 1,179,648
  u16*  fc1T  = (u16*)(ws + 65792 + 4718592); // 4,718,592
  u16*  fc2T  = (u16*)(ws + 65792 + 9437184); // 4,718,592
  const size_t B0 = 38535168;                 // 25088*768*2
  u16*  buf0  = (u16*)(ws + 14221568);        // shortcut / xs (in-place)
  u16*  buf1  = (u16*)(ws + 14221568 + B0);   // LN outputs
  char* scr   = ws + 14221568 + 2 * B0;       // per-chunk scratch

  // params offsets (u16)
  u16 *p_n1w = P, *p_n1b = P + 768, *p_qkvb = P + 1536, *p_projb = P + 3840;
  u16 *p_n2w = P + 4608, *p_n2b = P + 5376, *p_fc1b = P + 6144;
  u16 *p_fc2b = P + 9216, *p_g1 = P + 9984, *p_g2 = P + 10752, *p_bt = P + 11520;

  dim3 b256(256), bw(32, 8);
  detect_kernel<<<dim3(1), b256, 0, stream>>>((const u16*)x, flag);
  cvt_params_kernel<<<dim3(80), b256, 0, stream>>>(
      n1w, n1b, qkv_b, proj_b, n2w, n2b, fc1_b, fc2_b, gamma1, gamma2, btab,
      P, flag);
  wtr_kernel<<<dim3(72, 24), bw, 0, stream>>>(qkv_w, qkvT, 768, 2304, flag);
  wtr_kernel<<<dim3(24, 24), bw, 0, stream>>>(proj_w, projT, 768, 768, flag);
  wtr_kernel<<<dim3(96, 24), bw, 0, stream>>>(fc1_w, fc1T, 768, 3072, flag);
  wtr_kernel<<<dim3(24, 96), bw, 0, stream>>>(fc2_w, fc2T, 3072, 768, flag);

  tin_kernel<<<dim3(12, 56, 8), b256, 0, stream>>>(x, buf0, flag);
  ln_kernel<<<dim3(25088), b256, 0, stream>>>(buf0, p_n1w, p_n1b, buf1);

  for (int hc = 0; hc < c; ++hc) {
    size_t ro = (size_t)hc * R * 768;
    u16* qC = (u16*)scr;                       // R x 2304
    u16* aC = (u16*)(scr + (size_t)R * 4608);  // R x 768
    gemm_kernel<0><<<dim3(18, R / 128), b256, 0, stream>>>(
        buf1 + ro, qkvT, p_qkvb, nullptr, qC, 2304, 768);
    attn_kernel<<<dim3(WN * 12), b256, 0, stream>>>(qC, p_bt, aC);
    gemm_kernel<1><<<dim3(6, R / 128), b256, 0, stream>>>(
        aC, projT, p_projb, p_g1, buf0 + ro, 768, 768);
  }

  ln_kernel<<<dim3(25088), b256, 0, stream>>>(buf0, p_n2w, p_n2b, buf1);

  for (int hc = 0; hc < c; ++hc) {
    size_t ro = (size_t)hc * R * 768;
    u16* gC = (u16*)scr;                       // R x 3072
    gemm_kernel<2><<<dim3(24, R / 128), b256, 0, stream>>>(
        buf1 + ro, fc1T, p_fc1b, nullptr, gC, 3072, 768);
    gemm_kernel<1><<<dim3(6, R / 128), b256, 0, stream>>>(
        gC, fc2T, p_fc2b, p_g2, buf0 + ro, 768, 3072);
  }

  tout_kernel<<<dim3(12, 56, 8), b256, 0, stream>>>(buf0, d_out, flag);
}

// Round 4
// 1050.671 us; speedup vs baseline: 1.0416x; 1.0416x over previous
//
#include <hip/hip_runtime.h>
#include <cstdint>
#include <cstddef>

// ---------------------------------------------------------------------------
// HiERABlock, MI355X.  Dtype-adaptive (fp32/bf16 inputs, flag sniffed on
// device).  Internal pipeline all bf16, "windowed row order".
// GEMMs: A (MxK) bf16 row-major x BT (NxK) bf16 row-major, MFMA 16x16x32,
// m97-style global_load_lds staging + XCD-aware swizzle (blocks sharing an
// A-panel land on one XCD: id%8 round-robin model).
// ---------------------------------------------------------------------------

typedef unsigned short u16;
typedef short short8 __attribute__((ext_vector_type(8)));
typedef float floatx4 __attribute__((ext_vector_type(4)));

static __device__ __forceinline__ float bf2f(u16 u) {
  return __uint_as_float(((unsigned)u) << 16);
}
static __device__ __forceinline__ u16 f2bf(float f) {
  unsigned u = __float_as_uint(f);
  return (u16)((u + 0x7FFFu + ((u >> 16) & 1u)) >> 16);
}
static __device__ __forceinline__ float ldin(const void* p, size_t i, int isf) {
  return isf ? ((const float*)p)[i] : bf2f(((const u16*)p)[i]);
}
static __device__ __forceinline__ void gload_lds16(const void* g, void* l) {
  __builtin_amdgcn_global_load_lds(
      (const __attribute__((address_space(1))) void*)g,
      (__attribute__((address_space(3))) void*)l, 16, 0, 0);
}

// ---- dtype detector --------------------------------------------------------
__global__ __launch_bounds__(256) void detect_kernel(const u16* __restrict__ x,
                                                     int* __restrict__ flag) {
  __shared__ int tot;
  if (threadIdx.x == 0) tot = 0;
  __syncthreads();
  int cnt = 0;
  for (int i = threadIdx.x; i < 4096; i += 256) {
    int e = (x[i] >> 7) & 0xFF;
    if (e >= 0xC1) cnt++;
  }
  atomicAdd(&tot, cnt);
  __syncthreads();
  if (threadIdx.x == 0) flag[0] = (tot > 16) ? 1 : 0;
}

// ---- convert small params to bf16 ------------------------------------------
__global__ __launch_bounds__(256) void cvt_params_kernel(
    const void* n1w, const void* n1b, const void* qkvb, const void* projb,
    const void* n2w, const void* n2b, const void* fc1b, const void* fc2b,
    const void* g1, const void* g2, const void* bt, u16* __restrict__ P,
    const int* __restrict__ flag) {
  int isf = *flag;
  int i = blockIdx.x * 256 + threadIdx.x;
  const void* src; int off;
  if      (i < 768)   { src = n1w;   off = i; }
  else if (i < 1536)  { src = n1b;   off = i - 768; }
  else if (i < 3840)  { src = qkvb;  off = i - 1536; }
  else if (i < 4608)  { src = projb; off = i - 3840; }
  else if (i < 5376)  { src = n2w;   off = i - 4608; }
  else if (i < 6144)  { src = n2b;   off = i - 5376; }
  else if (i < 9216)  { src = fc1b;  off = i - 6144; }
  else if (i < 9984)  { src = fc2b;  off = i - 9216; }
  else if (i < 10752) { src = g1;    off = i - 9984; }
  else if (i < 11520) { src = g2;    off = i - 10752; }
  else if (i < 20268) { src = bt;    off = i - 11520; }
  else return;
  P[i] = f2bf(ldin(src, off, isf));
}

// ---- weight transpose ------------------------------------------------------
__global__ __launch_bounds__(256) void wtr_kernel(const void* __restrict__ W,
                                                  u16* __restrict__ WT,
                                                  int K, int N,
                                                  const int* __restrict__ flag) {
  int isf = *flag;
  __shared__ u16 tl[32][33];
  int tx = threadIdx.x, ty = threadIdx.y;
  int n0 = blockIdx.x * 32, k0 = blockIdx.y * 32;
#pragma unroll
  for (int j = 0; j < 32; j += 8)
    tl[ty + j][tx] = f2bf(ldin(W, (size_t)(k0 + ty + j) * N + n0 + tx, isf));
  __syncthreads();
#pragma unroll
  for (int j = 0; j < 32; j += 8)
    WT[(size_t)(n0 + ty + j) * K + k0 + tx] = tl[tx][ty + j];
}

// ---- input permute ---------------------------------------------------------
__global__ __launch_bounds__(256) void tin_kernel(const void* __restrict__ x,
                                                  u16* __restrict__ sc,
                                                  const int* __restrict__ flag) {
  int isf = *flag;
  int cc = blockIdx.x, h = blockIdx.y, b = blockIdx.z;  // grid (12,56,8)
  __shared__ u16 tile[64 * 57];
  int tid = threadIdx.x;
  for (int i = tid; i < 64 * 56; i += 256) {
    int ci = i / 56, w = i - ci * 56;
    tile[ci * 57 + w] =
        f2bf(ldin(x, (((size_t)b * 768 + cc * 64 + ci) * 56 + h) * 56 + w, isf));
  }
  __syncthreads();
  int hb = h / 14, hi = h - hb * 14;
  for (int i = tid; i < 56 * 64; i += 256) {
    int w = i >> 6, ci = i & 63;
    int wb = w / 14, wj = w - wb * 14;
    int r = (b * 16 + hb * 4 + wb) * 196 + hi * 14 + wj;
    sc[(size_t)r * 768 + cc * 64 + ci] = tile[ci * 57 + w];
  }
}

// ---- output permute --------------------------------------------------------
__global__ __launch_bounds__(256) void tout_kernel(const u16* __restrict__ src,
                                                   void* __restrict__ out,
                                                   const int* __restrict__ flag) {
  int isf = *flag;
  int cc = blockIdx.x, h = blockIdx.y, b = blockIdx.z;
  __shared__ u16 tile[64 * 57];
  int tid = threadIdx.x;
  int hb = h / 14, hi = h - hb * 14;
  for (int i = tid; i < 56 * 64; i += 256) {
    int w = i >> 6, ci = i & 63;
    int wb = w / 14, wj = w - wb * 14;
    int r = (b * 16 + hb * 4 + wb) * 196 + hi * 14 + wj;
    tile[ci * 57 + w] = src[(size_t)r * 768 + cc * 64 + ci];
  }
  __syncthreads();
  for (int i = tid; i < 64 * 56; i += 256) {
    int ci = i / 56, w = i - ci * 56;
    size_t o = (((size_t)b * 768 + cc * 64 + ci) * 56 + h) * 56 + w;
    if (isf) ((float*)out)[o] = bf2f(tile[ci * 57 + w]);
    else     ((u16*)out)[o]   = tile[ci * 57 + w];
  }
}

// ---- LayerNorm over C=768 --------------------------------------------------
__global__ __launch_bounds__(256) void ln_kernel(const u16* __restrict__ xin,
                                                 const u16* __restrict__ wt,
                                                 const u16* __restrict__ bs,
                                                 u16* __restrict__ out) {
  int row = blockIdx.x, t = threadIdx.x;
  const u16* xr = xin + (size_t)row * 768;
  float v0 = bf2f(xr[t]), v1 = bf2f(xr[t + 256]), v2 = bf2f(xr[t + 512]);
  float s1 = v0 + v1 + v2;
  float s2 = v0 * v0 + v1 * v1 + v2 * v2;
#pragma unroll
  for (int off = 32; off > 0; off >>= 1) {
    s1 += __shfl_xor(s1, off);
    s2 += __shfl_xor(s2, off);
  }
  __shared__ float p1[4], p2[4];
  if ((t & 63) == 0) { p1[t >> 6] = s1; p2[t >> 6] = s2; }
  __syncthreads();
  float S1 = p1[0] + p1[1] + p1[2] + p1[3];
  float S2 = p2[0] + p2[1] + p2[2] + p2[3];
  float mu = S1 * (1.f / 768.f);
  float var = S2 * (1.f / 768.f) - mu * mu;
  float rs = rsqrtf(var + 1e-5f);
  u16* orow = out + (size_t)row * 768;
  orow[t]       = f2bf((v0 - mu) * rs * bf2f(wt[t])       + bf2f(bs[t]));
  orow[t + 256] = f2bf((v1 - mu) * rs * bf2f(wt[t + 256]) + bf2f(bs[t + 256]));
  orow[t + 512] = f2bf((v2 - mu) * rs * bf2f(wt[t + 512]) + bf2f(bs[t + 512]));
}

// ---- GEMM with XCD swizzle: 1-D grid, id -> (x, y) s.t. blocks sharing an
// A-panel (same y, all x) have ids spaced by 8 => same XCD L2. --------------
template <int EPI>
__global__ __launch_bounds__(256) void gemm_kernel(
    const u16* __restrict__ A, const u16* __restrict__ BT,
    const u16* __restrict__ bias, const u16* __restrict__ gamma,
    u16* out, int N, int K, int NX, int NY) {
  int bid = blockIdx.x;
  int r8 = bid & 7, q = bid >> 3;
  int xb = q % NX, yb = (q / NX) * 8 + r8;
  if (yb >= NY) return;

  __shared__ u16 As[128 * 32];
  __shared__ u16 Bs[128 * 32];
  int tid = threadIdx.x;
  int w = tid >> 6, l = tid & 63;
  int lane15 = l & 15, quad = l >> 4;
  int m0 = yb * 128, n0 = xb * 128;
  int wm = w & 1, wn = w >> 1;
  floatx4 acc[4][4];
#pragma unroll
  for (int i = 0; i < 4; i++)
#pragma unroll
    for (int j = 0; j < 4; j++)
#pragma unroll
      for (int e = 0; e < 4; e++) acc[i][j][e] = 0.f;

  const u16* Abase = A + (size_t)m0 * K;
  const u16* Bbase = BT + (size_t)n0 * K;
  int rseg = l >> 2, ch = l & 3;

  for (int kt = 0; kt < K; kt += 32) {
    __syncthreads();
#pragma unroll
    for (int sI = 0; sI < 2; ++sI) {
      int s = w * 2 + sI;
      gload_lds16(Abase + (size_t)(s * 16 + rseg) * K + kt + ch * 8, &As[s * 512]);
      gload_lds16(Bbase + (size_t)(s * 16 + rseg) * K + kt + ch * 8, &Bs[s * 512]);
    }
    __syncthreads();
    short8 af[4], bf[4];
#pragma unroll
    for (int mi = 0; mi < 4; ++mi)
      af[mi] = *(const short8*)&As[(wm * 64 + mi * 16 + lane15) * 32 + quad * 8];
#pragma unroll
    for (int ni = 0; ni < 4; ++ni)
      bf[ni] = *(const short8*)&Bs[(wn * 64 + ni * 16 + lane15) * 32 + quad * 8];
#pragma unroll
    for (int mi = 0; mi < 4; ++mi)
#pragma unroll
      for (int ni = 0; ni < 4; ++ni)
        acc[mi][ni] = __builtin_amdgcn_mfma_f32_16x16x32_bf16(
            af[mi], bf[ni], acc[mi][ni], 0, 0, 0);
  }

#pragma unroll
  for (int mi = 0; mi < 4; ++mi) {
    int row0 = m0 + wm * 64 + mi * 16 + quad * 4;
#pragma unroll
    for (int ni = 0; ni < 4; ++ni) {
      int col = n0 + wn * 64 + ni * 16 + lane15;
      float bv = bf2f(bias[col]);
#pragma unroll
      for (int reg = 0; reg < 4; ++reg) {
        int row = row0 + reg;
        float v = acc[mi][ni][reg] + bv;
        size_t idx = (size_t)row * N + col;
        if (EPI == 0) {
          out[idx] = f2bf(v);
        } else if (EPI == 1) {
          out[idx] = f2bf(bf2f(out[idx]) + bf2f(gamma[col]) * v);
        } else {
          out[idx] = f2bf(0.5f * v * (1.f + erff(v * 0.70710678118f)));
        }
      }
    }
  }
}

// ---- window attention ------------------------------------------------------
__global__ __launch_bounds__(256) void attn_kernel(const u16* __restrict__ qkv,
                                                   const u16* __restrict__ btab,
                                                   u16* __restrict__ out) {
  __shared__ __align__(16) u16 VT[64 * 232];      // cols 196..223 zeroed
  __shared__ __align__(16) u16 Pa[4 * 2 * 512];   // per-wave double-buffered P
  __shared__ float bS[729];
  int bid = blockIdx.x;
  int win = bid / 12, h = bid - win * 12;
  int tid = threadIdx.x, w = tid >> 6, l = tid & 63;
  int lane15 = l & 15, quad = l >> 4;
  const u16* qbase = qkv + (size_t)win * 196 * 2304;

  for (int i = tid; i < 64 * 28; i += 256) {
    int d = i / 28, m = i - d * 28;
    VT[d * 232 + 196 + m] = 0;
  }
  for (int i = tid; i < 196 * 64; i += 256) {
    int m = i >> 6, d = i & 63;
    VT[d * 232 + m] = qbase[(size_t)m * 2304 + 1536 + h * 64 + d];
  }
  for (int i = tid; i < 729; i += 256) bS[i] = bf2f(btab[i * 12 + h]);
  __syncthreads();

  u16* Pw = Pa + w * 1024;
  for (int rt = w; rt < 13; rt += 4) {
    floatx4 acc[13];
#pragma unroll
    for (int nt = 0; nt < 13; ++nt)
#pragma unroll
      for (int e = 0; e < 4; ++e) acc[nt][e] = 0.f;

    int rq = rt * 16 + lane15;
    bool qok = rq < 196;
#pragma unroll
    for (int kk = 0; kk < 2; ++kk) {
      short8 qf;
      if (qok)
        qf = *(const short8*)&qbase[(size_t)rq * 2304 + h * 64 + kk * 32 + quad * 8];
      else
#pragma unroll
        for (int e = 0; e < 8; ++e) qf[e] = 0;
#pragma unroll
      for (int nt = 0; nt < 13; ++nt) {
        int n = nt * 16 + lane15;  // rows 196..207 over-read (allocated, masked)
        short8 kf = *(const short8*)&qbase[(size_t)n * 2304 + 768 + h * 64 + kk * 32 + quad * 8];
        acc[nt] = __builtin_amdgcn_mfma_f32_16x16x32_bf16(qf, kf, acc[nt], 0, 0, 0);
      }
    }

    int i1[4], j1[4]; bool rv[4]; float mx[4], sm[4];
#pragma unroll
    for (int reg = 0; reg < 4; ++reg) {
      int r = rt * 16 + quad * 4 + reg;
      i1[reg] = r / 14; j1[reg] = r - i1[reg] * 14;
      rv[reg] = r < 196; mx[reg] = -1e30f; sm[reg] = 0.f;
    }
#pragma unroll
    for (int nt = 0; nt < 13; ++nt) {
      int cc = nt * 16 + lane15;
      bool cv = cc < 196;
      int i2 = cc / 14, j2 = cc - i2 * 14;
#pragma unroll
      for (int reg = 0; reg < 4; ++reg) {
        float v;
        if (cv) {
          v = acc[nt][reg] * 0.125f;
          if (rv[reg]) v += bS[(i1[reg] - i2 + 13) * 27 + (j1[reg] - j2 + 13)];
        } else v = -1e30f;
        acc[nt][reg] = v;
        mx[reg] = fmaxf(mx[reg], v);
      }
    }
#pragma unroll
    for (int reg = 0; reg < 4; ++reg)
#pragma unroll
      for (int off = 1; off < 16; off <<= 1)
        mx[reg] = fmaxf(mx[reg], __shfl_xor(mx[reg], off));
#pragma unroll
    for (int nt = 0; nt < 13; ++nt)
#pragma unroll
      for (int reg = 0; reg < 4; ++reg) {
        float p = __expf(acc[nt][reg] - mx[reg]);
        acc[nt][reg] = p; sm[reg] += p;
      }
#pragma unroll
    for (int reg = 0; reg < 4; ++reg) {
#pragma unroll
      for (int off = 1; off < 16; off <<= 1) sm[reg] += __shfl_xor(sm[reg], off);
      sm[reg] = 1.f / sm[reg];
    }

    floatx4 oa[4];
#pragma unroll
    for (int dt = 0; dt < 4; ++dt)
#pragma unroll
      for (int e = 0; e < 4; ++e) oa[dt][e] = 0.f;
#pragma unroll
    for (int kk = 0; kk < 7; ++kk) {
      u16* Pb = Pw + (kk & 1) * 512;
#pragma unroll
      for (int p = 0; p < 2; ++p) {
        int nt = kk * 2 + p;
#pragma unroll
        for (int reg = 0; reg < 4; ++reg) {
          float v = (nt < 13) ? acc[nt][reg] * sm[reg] : 0.f;
          Pb[(quad * 4 + reg) * 32 + p * 16 + lane15] = f2bf(v);
        }
      }
      asm volatile("s_waitcnt lgkmcnt(0)" ::: "memory");
      short8 pf = *(const short8*)&Pb[lane15 * 32 + quad * 8];
#pragma unroll
      for (int dt = 0; dt < 4; ++dt) {
        short8 vf = *(const short8*)&VT[(dt * 16 + lane15) * 232 + kk * 32 + quad * 8];
        oa[dt] = __builtin_amdgcn_mfma_f32_16x16x32_bf16(pf, vf, oa[dt], 0, 0, 0);
      }
    }
#pragma unroll
    for (int dt = 0; dt < 4; ++dt)
#pragma unroll
      for (int reg = 0; reg < 4; ++reg) {
        int r = rt * 16 + quad * 4 + reg;
        if (r < 196)
          out[((size_t)win * 196 + r) * 768 + h * 64 + dt * 16 + lane15] =
              f2bf(oa[dt][reg]);
      }
  }
}

// ---------------------------------------------------------------------------
static inline int gemm_grid(int NX, int NY) { return NX * ((NY + 7) / 8) * 8; }

extern "C" void kernel_launch(void* const* d_in, const int* in_sizes, int n_in,
                              void* d_out, int out_size, void* d_ws, size_t ws_size,
                              hipStream_t stream) {
  const void* x      = d_in[0];
  const void* n1w    = d_in[1];
  const void* n1b    = d_in[2];
  const void* qkv_w  = d_in[3];
  const void* qkv_b  = d_in[4];
  const void* btab   = d_in[5];
  const void* proj_w = d_in[6];
  const void* proj_b = d_in[7];
  const void* n2w    = d_in[8];
  const void* n2b    = d_in[9];
  const void* fc1_w  = d_in[10];
  const void* fc1_b  = d_in[11];
  const void* fc2_w  = d_in[12];
  const void* fc2_b  = d_in[13];
  const void* gamma1 = d_in[14];
  const void* gamma2 = d_in[15];
  (void)in_sizes; (void)n_in; (void)out_size;

  int c;
  if      (ws_size >= 245432576ull) c = 1;
  else if (ws_size >= 168362240ull) c = 2;
  else                              c = 4;
  const int R = 25088 / c;
  const int WN = 128 / c;
  const int NY = R / 128;

  char* ws = (char*)d_ws;
  int*  flag  = (int*)ws;
  u16*  P     = (u16*)(ws + 256);
  u16*  qkvT  = (u16*)(ws + 65792);
  u16*  projT = (u16*)(ws + 65792 + 3538944);
  u16*  fc1T  = (u16*)(ws + 65792 + 4718592);
  u16*  fc2T  = (u16*)(ws + 65792 + 9437184);
  const size_t B0 = 38535168;
  u16*  buf0  = (u16*)(ws + 14221568);
  u16*  buf1  = (u16*)(ws + 14221568 + B0);
  char* scr   = ws + 14221568 + 2 * B0;

  u16 *p_n1w = P, *p_n1b = P + 768, *p_qkvb = P + 1536, *p_projb = P + 3840;
  u16 *p_n2w = P + 4608, *p_n2b = P + 5376, *p_fc1b = P + 6144;
  u16 *p_fc2b = P + 9216, *p_g1 = P + 9984, *p_g2 = P + 10752, *p_bt = P + 11520;

  dim3 b256(256), bw(32, 8);
  detect_kernel<<<dim3(1), b256, 0, stream>>>((const u16*)x, flag);
  cvt_params_kernel<<<dim3(80), b256, 0, stream>>>(
      n1w, n1b, qkv_b, proj_b, n2w, n2b, fc1_b, fc2_b, gamma1, gamma2, btab,
      P, flag);
  wtr_kernel<<<dim3(72, 24), bw, 0, stream>>>(qkv_w, qkvT, 768, 2304, flag);
  wtr_kernel<<<dim3(24, 24), bw, 0, stream>>>(proj_w, projT, 768, 768, flag);
  wtr_kernel<<<dim3(96, 24), bw, 0, stream>>>(fc1_w, fc1T, 768, 3072, flag);
  wtr_kernel<<<dim3(24, 96), bw, 0, stream>>>(fc2_w, fc2T, 3072, 768, flag);

  tin_kernel<<<dim3(12, 56, 8), b256, 0, stream>>>(x, buf0, flag);
  ln_kernel<<<dim3(25088), b256, 0, stream>>>(buf0, p_n1w, p_n1b, buf1);

  for (int hc = 0; hc < c; ++hc) {
    size_t ro = (size_t)hc * R * 768;
    u16* qC = (u16*)scr;
    u16* aC = (u16*)(scr + (size_t)R * 4608);
    gemm_kernel<0><<<dim3(gemm_grid(18, NY)), b256, 0, stream>>>(
        buf1 + ro, qkvT, p_qkvb, nullptr, qC, 2304, 768, 18, NY);
    attn_kernel<<<dim3(WN * 12), b256, 0, stream>>>(qC, p_bt, aC);
    gemm_kernel<1><<<dim3(gemm_grid(6, NY)), b256, 0, stream>>>(
        aC, projT, p_projb, p_g1, buf0 + ro, 768, 768, 6, NY);
  }

  ln_kernel<<<dim3(25088), b256, 0, stream>>>(buf0, p_n2w, p_n2b, buf1);

  for (int hc = 0; hc < c; ++hc) {
    size_t ro = (size_t)hc * R * 768;
    u16* gC = (u16*)scr;
    gemm_kernel<2><<<dim3(gemm_grid(24, NY)), b256, 0, stream>>>(
        buf1 + ro, fc1T, p_fc1b, nullptr, gC, 3072, 768, 24, NY);
    gemm_kernel<1><<<dim3(gemm_grid(6, NY)), b256, 0, stream>>>(
        gC, fc2T, p_fc2b, p_g2, buf0 + ro, 768, 3072, 6, NY);
  }

  tout_kernel<<<dim3(12, 56, 8), b256, 0, stream>>>(buf0, d_out, flag);
}

// Round 5
// 1048.563 us; speedup vs baseline: 1.0437x; 1.0020x over previous
//
#include <hip/hip_runtime.h>
#include <cstdint>
#include <cstddef>

// ---------------------------------------------------------------------------
// HiERABlock, MI355X.  Dtype-adaptive (fp32/bf16 inputs, flag sniffed on
// device).  Internal pipeline all bf16, "windowed row order".
// GEMMs: A (MxK) bf16 row-major x BT (NxK) bf16 row-major, MFMA 16x16x32,
// m97-style global_load_lds staging + XCD swizzle.  EPI 0/2 epilogues repack
// the C tile through LDS for dwordx4 coalesced stores; GELU is tanh-form
// (erff was the VALU bottleneck: 63% VALUBusy on fc1).
// ---------------------------------------------------------------------------

typedef unsigned short u16;
typedef short short8 __attribute__((ext_vector_type(8)));
typedef float floatx4 __attribute__((ext_vector_type(4)));

static __device__ __forceinline__ float bf2f(u16 u) {
  return __uint_as_float(((unsigned)u) << 16);
}
static __device__ __forceinline__ u16 f2bf(float f) {
  unsigned u = __float_as_uint(f);
  return (u16)((u + 0x7FFFu + ((u >> 16) & 1u)) >> 16);
}
static __device__ __forceinline__ float ldin(const void* p, size_t i, int isf) {
  return isf ? ((const float*)p)[i] : bf2f(((const u16*)p)[i]);
}
static __device__ __forceinline__ void gload_lds16(const void* g, void* l) {
  __builtin_amdgcn_global_load_lds(
      (const __attribute__((address_space(1))) void*)g,
      (__attribute__((address_space(3))) void*)l, 16, 0, 0);
}
// tanh-form GELU: max |err| ~3e-4; downstream effect ~1e-9 (gamma2=1e-5)
static __device__ __forceinline__ float fast_gelu(float v) {
  float u2 = v * (1.5957691216f + 0.0713548163f * v * v);
  return v * (1.0f / (1.0f + __expf(-u2)));
}

// ---- dtype detector --------------------------------------------------------
__global__ __launch_bounds__(256) void detect_kernel(const u16* __restrict__ x,
                                                     int* __restrict__ flag) {
  __shared__ int tot;
  if (threadIdx.x == 0) tot = 0;
  __syncthreads();
  int cnt = 0;
  for (int i = threadIdx.x; i < 4096; i += 256) {
    int e = (x[i] >> 7) & 0xFF;
    if (e >= 0xC1) cnt++;
  }
  atomicAdd(&tot, cnt);
  __syncthreads();
  if (threadIdx.x == 0) flag[0] = (tot > 16) ? 1 : 0;
}

// ---- convert small params to bf16 ------------------------------------------
__global__ __launch_bounds__(256) void cvt_params_kernel(
    const void* n1w, const void* n1b, const void* qkvb, const void* projb,
    const void* n2w, const void* n2b, const void* fc1b, const void* fc2b,
    const void* g1, const void* g2, const void* bt, u16* __restrict__ P,
    const int* __restrict__ flag) {
  int isf = *flag;
  int i = blockIdx.x * 256 + threadIdx.x;
  const void* src; int off;
  if      (i < 768)   { src = n1w;   off = i; }
  else if (i < 1536)  { src = n1b;   off = i - 768; }
  else if (i < 3840)  { src = qkvb;  off = i - 1536; }
  else if (i < 4608)  { src = projb; off = i - 3840; }
  else if (i < 5376)  { src = n2w;   off = i - 4608; }
  else if (i < 6144)  { src = n2b;   off = i - 5376; }
  else if (i < 9216)  { src = fc1b;  off = i - 6144; }
  else if (i < 9984)  { src = fc2b;  off = i - 9216; }
  else if (i < 10752) { src = g1;    off = i - 9984; }
  else if (i < 11520) { src = g2;    off = i - 10752; }
  else if (i < 20268) { src = bt;    off = i - 11520; }
  else return;
  P[i] = f2bf(ldin(src, off, isf));
}

// ---- weight transpose ------------------------------------------------------
__global__ __launch_bounds__(256) void wtr_kernel(const void* __restrict__ W,
                                                  u16* __restrict__ WT,
                                                  int K, int N,
                                                  const int* __restrict__ flag) {
  int isf = *flag;
  __shared__ u16 tl[32][33];
  int tx = threadIdx.x, ty = threadIdx.y;
  int n0 = blockIdx.x * 32, k0 = blockIdx.y * 32;
#pragma unroll
  for (int j = 0; j < 32; j += 8)
    tl[ty + j][tx] = f2bf(ldin(W, (size_t)(k0 + ty + j) * N + n0 + tx, isf));
  __syncthreads();
#pragma unroll
  for (int j = 0; j < 32; j += 8)
    WT[(size_t)(n0 + ty + j) * K + k0 + tx] = tl[tx][ty + j];
}

// ---- input permute ---------------------------------------------------------
__global__ __launch_bounds__(256) void tin_kernel(const void* __restrict__ x,
                                                  u16* __restrict__ sc,
                                                  const int* __restrict__ flag) {
  int isf = *flag;
  int cc = blockIdx.x, h = blockIdx.y, b = blockIdx.z;  // grid (12,56,8)
  __shared__ u16 tile[64 * 57];
  int tid = threadIdx.x;
  for (int i = tid; i < 64 * 56; i += 256) {
    int ci = i / 56, w = i - ci * 56;
    tile[ci * 57 + w] =
        f2bf(ldin(x, (((size_t)b * 768 + cc * 64 + ci) * 56 + h) * 56 + w, isf));
  }
  __syncthreads();
  int hb = h / 14, hi = h - hb * 14;
  for (int i = tid; i < 56 * 64; i += 256) {
    int w = i >> 6, ci = i & 63;
    int wb = w / 14, wj = w - wb * 14;
    int r = (b * 16 + hb * 4 + wb) * 196 + hi * 14 + wj;
    sc[(size_t)r * 768 + cc * 64 + ci] = tile[ci * 57 + w];
  }
}

// ---- output permute --------------------------------------------------------
__global__ __launch_bounds__(256) void tout_kernel(const u16* __restrict__ src,
                                                   void* __restrict__ out,
                                                   const int* __restrict__ flag) {
  int isf = *flag;
  int cc = blockIdx.x, h = blockIdx.y, b = blockIdx.z;
  __shared__ u16 tile[64 * 57];
  int tid = threadIdx.x;
  int hb = h / 14, hi = h - hb * 14;
  for (int i = tid; i < 56 * 64; i += 256) {
    int w = i >> 6, ci = i & 63;
    int wb = w / 14, wj = w - wb * 14;
    int r = (b * 16 + hb * 4 + wb) * 196 + hi * 14 + wj;
    tile[ci * 57 + w] = src[(size_t)r * 768 + cc * 64 + ci];
  }
  __syncthreads();
  for (int i = tid; i < 64 * 56; i += 256) {
    int ci = i / 56, w = i - ci * 56;
    size_t o = (((size_t)b * 768 + cc * 64 + ci) * 56 + h) * 56 + w;
    if (isf) ((float*)out)[o] = bf2f(tile[ci * 57 + w]);
    else     ((u16*)out)[o]   = tile[ci * 57 + w];
  }
}

// ---- LayerNorm over C=768 --------------------------------------------------
__global__ __launch_bounds__(256) void ln_kernel(const u16* __restrict__ xin,
                                                 const u16* __restrict__ wt,
                                                 const u16* __restrict__ bs,
                                                 u16* __restrict__ out) {
  int row = blockIdx.x, t = threadIdx.x;
  const u16* xr = xin + (size_t)row * 768;
  float v0 = bf2f(xr[t]), v1 = bf2f(xr[t + 256]), v2 = bf2f(xr[t + 512]);
  float s1 = v0 + v1 + v2;
  float s2 = v0 * v0 + v1 * v1 + v2 * v2;
#pragma unroll
  for (int off = 32; off > 0; off >>= 1) {
    s1 += __shfl_xor(s1, off);
    s2 += __shfl_xor(s2, off);
  }
  __shared__ float p1[4], p2[4];
  if ((t & 63) == 0) { p1[t >> 6] = s1; p2[t >> 6] = s2; }
  __syncthreads();
  float S1 = p1[0] + p1[1] + p1[2] + p1[3];
  float S2 = p2[0] + p2[1] + p2[2] + p2[3];
  float mu = S1 * (1.f / 768.f);
  float var = S2 * (1.f / 768.f) - mu * mu;
  float rs = rsqrtf(var + 1e-5f);
  u16* orow = out + (size_t)row * 768;
  orow[t]       = f2bf((v0 - mu) * rs * bf2f(wt[t])       + bf2f(bs[t]));
  orow[t + 256] = f2bf((v1 - mu) * rs * bf2f(wt[t + 256]) + bf2f(bs[t + 256]));
  orow[t + 512] = f2bf((v2 - mu) * rs * bf2f(wt[t + 512]) + bf2f(bs[t + 512]));
}

// ---- GEMM with XCD swizzle. EPI 0: plain bf16 out. EPI 1: in-place
// layerscale residual (RMW). EPI 2: fast-gelu. EPI 0/2 use LDS C-repack
// for dwordx4 coalesced stores. -------------------------------------------
template <int EPI>
__global__ __launch_bounds__(256) void gemm_kernel(
    const u16* __restrict__ A, const u16* __restrict__ BT,
    const u16* __restrict__ bias, const u16* __restrict__ gamma,
    u16* out, int N, int K, int NX, int NY) {
  int bid = blockIdx.x;
  int r8 = bid & 7, q = bid >> 3;
  int xb = q % NX, yb = (q / NX) * 8 + r8;
  if (yb >= NY) return;

  __shared__ u16 As[128 * 32];
  __shared__ u16 Bs[128 * 32];
  int tid = threadIdx.x;
  int w = tid >> 6, l = tid & 63;
  int lane15 = l & 15, quad = l >> 4;
  int m0 = yb * 128, n0 = xb * 128;
  int wm = w & 1, wn = w >> 1;
  floatx4 acc[4][4];
#pragma unroll
  for (int i = 0; i < 4; i++)
#pragma unroll
    for (int j = 0; j < 4; j++)
#pragma unroll
      for (int e = 0; e < 4; e++) acc[i][j][e] = 0.f;

  const u16* Abase = A + (size_t)m0 * K;
  const u16* Bbase = BT + (size_t)n0 * K;
  int rseg = l >> 2, ch = l & 3;

  for (int kt = 0; kt < K; kt += 32) {
    __syncthreads();
#pragma unroll
    for (int sI = 0; sI < 2; ++sI) {
      int s = w * 2 + sI;
      gload_lds16(Abase + (size_t)(s * 16 + rseg) * K + kt + ch * 8, &As[s * 512]);
      gload_lds16(Bbase + (size_t)(s * 16 + rseg) * K + kt + ch * 8, &Bs[s * 512]);
    }
    __syncthreads();
    short8 af[4], bf[4];
#pragma unroll
    for (int mi = 0; mi < 4; ++mi)
      af[mi] = *(const short8*)&As[(wm * 64 + mi * 16 + lane15) * 32 + quad * 8];
#pragma unroll
    for (int ni = 0; ni < 4; ++ni)
      bf[ni] = *(const short8*)&Bs[(wn * 64 + ni * 16 + lane15) * 32 + quad * 8];
#pragma unroll
    for (int mi = 0; mi < 4; ++mi)
#pragma unroll
      for (int ni = 0; ni < 4; ++ni)
        acc[mi][ni] = __builtin_amdgcn_mfma_f32_16x16x32_bf16(
            af[mi], bf[ni], acc[mi][ni], 0, 0, 0);
  }

  if constexpr (EPI == 1) {
#pragma unroll
    for (int mi = 0; mi < 4; ++mi) {
      int row0 = m0 + wm * 64 + mi * 16 + quad * 4;
#pragma unroll
      for (int ni = 0; ni < 4; ++ni) {
        int col = n0 + wn * 64 + ni * 16 + lane15;
        float bv = bf2f(bias[col]);
        float gv = bf2f(gamma[col]);
#pragma unroll
        for (int reg = 0; reg < 4; ++reg) {
          size_t idx = (size_t)(row0 + reg) * N + col;
          float v = acc[mi][ni][reg] + bv;
          out[idx] = f2bf(bf2f(out[idx]) + gv * v);
        }
      }
    }
  } else {
    // repack C tile through LDS (padded stride 136), then coalesced stores
    __shared__ __align__(16) u16 Cs[128 * 136];
    __syncthreads();
#pragma unroll
    for (int mi = 0; mi < 4; ++mi) {
      int rl0 = wm * 64 + mi * 16 + quad * 4;
#pragma unroll
      for (int ni = 0; ni < 4; ++ni) {
        int cl = wn * 64 + ni * 16 + lane15;
        float bv = bf2f(bias[n0 + cl]);
#pragma unroll
        for (int reg = 0; reg < 4; ++reg) {
          float v = acc[mi][ni][reg] + bv;
          if (EPI == 2) v = fast_gelu(v);
          Cs[(rl0 + reg) * 136 + cl] = f2bf(v);
        }
      }
    }
    __syncthreads();
    int rr = tid >> 4, cc8 = (tid & 15) * 8;
#pragma unroll
    for (int chk = 0; chk < 8; ++chk) {
      int row = chk * 16 + rr;
      short8 val = *(const short8*)&Cs[row * 136 + cc8];
      *(short8*)(out + (size_t)(m0 + row) * N + n0 + cc8) = val;
    }
  }
}

// ---- window attention ------------------------------------------------------
__global__ __launch_bounds__(256) void attn_kernel(const u16* __restrict__ qkv,
                                                   const u16* __restrict__ btab,
                                                   u16* __restrict__ out) {
  __shared__ __align__(16) u16 VT[64 * 232];      // cols 196..223 zeroed
  __shared__ __align__(16) u16 Pa[4 * 2 * 512];   // per-wave double-buffered P
  __shared__ float bS[729];
  int bid = blockIdx.x;
  int win = bid / 12, h = bid - win * 12;
  int tid = threadIdx.x, w = tid >> 6, l = tid & 63;
  int lane15 = l & 15, quad = l >> 4;
  const u16* qbase = qkv + (size_t)win * 196 * 2304;

  for (int i = tid; i < 64 * 28; i += 256) {
    int d = i / 28, m = i - d * 28;
    VT[d * 232 + 196 + m] = 0;
  }
  for (int i = tid; i < 196 * 64; i += 256) {
    int m = i >> 6, d = i & 63;
    VT[d * 232 + m] = qbase[(size_t)m * 2304 + 1536 + h * 64 + d];
  }
  for (int i = tid; i < 729; i += 256) bS[i] = bf2f(btab[i * 12 + h]);
  __syncthreads();

  u16* Pw = Pa + w * 1024;
  for (int rt = w; rt < 13; rt += 4) {
    floatx4 acc[13];
#pragma unroll
    for (int nt = 0; nt < 13; ++nt)
#pragma unroll
      for (int e = 0; e < 4; ++e) acc[nt][e] = 0.f;

    int rq = rt * 16 + lane15;
    bool qok = rq < 196;
#pragma unroll
    for (int kk = 0; kk < 2; ++kk) {
      short8 qf;
      if (qok)
        qf = *(const short8*)&qbase[(size_t)rq * 2304 + h * 64 + kk * 32 + quad * 8];
      else
#pragma unroll
        for (int e = 0; e < 8; ++e) qf[e] = 0;
#pragma unroll
      for (int nt = 0; nt < 13; ++nt) {
        int n = nt * 16 + lane15;  // rows 196..207 over-read (allocated, masked)
        short8 kf = *(const short8*)&qbase[(size_t)n * 2304 + 768 + h * 64 + kk * 32 + quad * 8];
        acc[nt] = __builtin_amdgcn_mfma_f32_16x16x32_bf16(qf, kf, acc[nt], 0, 0, 0);
      }
    }

    int i1[4], j1[4]; bool rv[4]; float mx[4], sm[4];
#pragma unroll
    for (int reg = 0; reg < 4; ++reg) {
      int r = rt * 16 + quad * 4 + reg;
      i1[reg] = r / 14; j1[reg] = r - i1[reg] * 14;
      rv[reg] = r < 196; mx[reg] = -1e30f; sm[reg] = 0.f;
    }
#pragma unroll
    for (int nt = 0; nt < 13; ++nt) {
      int cc = nt * 16 + lane15;
      bool cv = cc < 196;
      int i2 = cc / 14, j2 = cc - i2 * 14;
#pragma unroll
      for (int reg = 0; reg < 4; ++reg) {
        float v;
        if (cv) {
          v = acc[nt][reg] * 0.125f;
          if (rv[reg]) v += bS[(i1[reg] - i2 + 13) * 27 + (j1[reg] - j2 + 13)];
        } else v = -1e30f;
        acc[nt][reg] = v;
        mx[reg] = fmaxf(mx[reg], v);
      }
    }
#pragma unroll
    for (int reg = 0; reg < 4; ++reg)
#pragma unroll
      for (int off = 1; off < 16; off <<= 1)
        mx[reg] = fmaxf(mx[reg], __shfl_xor(mx[reg], off));
#pragma unroll
    for (int nt = 0; nt < 13; ++nt)
#pragma unroll
      for (int reg = 0; reg < 4; ++reg) {
        float p = __expf(acc[nt][reg] - mx[reg]);
        acc[nt][reg] = p; sm[reg] += p;
      }
#pragma unroll
    for (int reg = 0; reg < 4; ++reg) {
#pragma unroll
      for (int off = 1; off < 16; off <<= 1) sm[reg] += __shfl_xor(sm[reg], off);
      sm[reg] = 1.f / sm[reg];
    }

    floatx4 oa[4];
#pragma unroll
    for (int dt = 0; dt < 4; ++dt)
#pragma unroll
      for (int e = 0; e < 4; ++e) oa[dt][e] = 0.f;
#pragma unroll
    for (int kk = 0; kk < 7; ++kk) {
      u16* Pb = Pw + (kk & 1) * 512;
#pragma unroll
      for (int p = 0; p < 2; ++p) {
        int nt = kk * 2 + p;
#pragma unroll
        for (int reg = 0; reg < 4; ++reg) {
          float v = (nt < 13) ? acc[nt][reg] * sm[reg] : 0.f;
          Pb[(quad * 4 + reg) * 32 + p * 16 + lane15] = f2bf(v);
        }
      }
      asm volatile("s_waitcnt lgkmcnt(0)" ::: "memory");
      short8 pf = *(const short8*)&Pb[lane15 * 32 + quad * 8];
#pragma unroll
      for (int dt = 0; dt < 4; ++dt) {
        short8 vf = *(const short8*)&VT[(dt * 16 + lane15) * 232 + kk * 32 + quad * 8];
        oa[dt] = __builtin_amdgcn_mfma_f32_16x16x32_bf16(pf, vf, oa[dt], 0, 0, 0);
      }
    }
#pragma unroll
    for (int dt = 0; dt < 4; ++dt)
#pragma unroll
      for (int reg = 0; reg < 4; ++reg) {
        int r = rt * 16 + quad * 4 + reg;
        if (r < 196)
          out[((size_t)win * 196 + r) * 768 + h * 64 + dt * 16 + lane15] =
              f2bf(oa[dt][reg]);
      }
  }
}

// ---------------------------------------------------------------------------
static inline int gemm_grid(int NX, int NY) { return NX * ((NY + 7) / 8) * 8; }

extern "C" void kernel_launch(void* const* d_in, const int* in_sizes, int n_in,
                              void* d_out, int out_size, void* d_ws, size_t ws_size,
                              hipStream_t stream) {
  const void* x      = d_in[0];
  const void* n1w    = d_in[1];
  const void* n1b    = d_in[2];
  const void* qkv_w  = d_in[3];
  const void* qkv_b  = d_in[4];
  const void* btab   = d_in[5];
  const void* proj_w = d_in[6];
  const void* proj_b = d_in[7];
  const void* n2w    = d_in[8];
  const void* n2b    = d_in[9];
  const void* fc1_w  = d_in[10];
  const void* fc1_b  = d_in[11];
  const void* fc2_w  = d_in[12];
  const void* fc2_b  = d_in[13];
  const void* gamma1 = d_in[14];
  const void* gamma2 = d_in[15];
  (void)in_sizes; (void)n_in; (void)out_size;

  int c;
  if      (ws_size >= 245432576ull) c = 1;
  else if (ws_size >= 168362240ull) c = 2;
  else                              c = 4;
  const int R = 25088 / c;
  const int WN = 128 / c;
  const int NY = R / 128;

  char* ws = (char*)d_ws;
  int*  flag  = (int*)ws;
  u16*  P     = (u16*)(ws + 256);
  u16*  qkvT  = (u16*)(ws + 65792);
  u16*  projT = (u16*)(ws + 65792 + 3538944);
  u16*  fc1T  = (u16*)(ws + 65792 + 4718592);
  u16*  fc2T  = (u16*)(ws + 65792 + 9437184);
  const size_t B0 = 38535168;
  u16*  buf0  = (u16*)(ws + 14221568);
  u16*  buf1  = (u16*)(ws + 14221568 + B0);
  char* scr   = ws + 14221568 + 2 * B0;

  u16 *p_n1w = P, *p_n1b = P + 768, *p_qkvb = P + 1536, *p_projb = P + 3840;
  u16 *p_n2w = P + 4608, *p_n2b = P + 5376, *p_fc1b = P + 6144;
  u16 *p_fc2b = P + 9216, *p_g1 = P + 9984, *p_g2 = P + 10752, *p_bt = P + 11520;

  dim3 b256(256), bw(32, 8);
  detect_kernel<<<dim3(1), b256, 0, stream>>>((const u16*)x, flag);
  cvt_params_kernel<<<dim3(80), b256, 0, stream>>>(
      n1w, n1b, qkv_b, proj_b, n2w, n2b, fc1_b, fc2_b, gamma1, gamma2, btab,
      P, flag);
  wtr_kernel<<<dim3(72, 24), bw, 0, stream>>>(qkv_w, qkvT, 768, 2304, flag);
  wtr_kernel<<<dim3(24, 24), bw, 0, stream>>>(proj_w, projT, 768, 768, flag);
  wtr_kernel<<<dim3(96, 24), bw, 0, stream>>>(fc1_w, fc1T, 768, 3072, flag);
  wtr_kernel<<<dim3(24, 96), bw, 0, stream>>>(fc2_w, fc2T, 3072, 768, flag);

  tin_kernel<<<dim3(12, 56, 8), b256, 0, stream>>>(x, buf0, flag);
  ln_kernel<<<dim3(25088), b256, 0, stream>>>(buf0, p_n1w, p_n1b, buf1);

  for (int hc = 0; hc < c; ++hc) {
    size_t ro = (size_t)hc * R * 768;
    u16* qC = (u16*)scr;
    u16* aC = (u16*)(scr + (size_t)R * 4608);
    gemm_kernel<0><<<dim3(gemm_grid(18, NY)), b256, 0, stream>>>(
        buf1 + ro, qkvT, p_qkvb, nullptr, qC, 2304, 768, 18, NY);
    attn_kernel<<<dim3(WN * 12), b256, 0, stream>>>(qC, p_bt, aC);
    gemm_kernel<1><<<dim3(gemm_grid(6, NY)), b256, 0, stream>>>(
        aC, projT, p_projb, p_g1, buf0 + ro, 768, 768, 6, NY);
  }

  ln_kernel<<<dim3(25088), b256, 0, stream>>>(buf0, p_n2w, p_n2b, buf1);

  for (int hc = 0; hc < c; ++hc) {
    size_t ro = (size_t)hc * R * 768;
    u16* gC = (u16*)scr;
    gemm_kernel<2><<<dim3(gemm_grid(24, NY)), b256, 0, stream>>>(
        buf1 + ro, fc1T, p_fc1b, nullptr, gC, 3072, 768, 24, NY);
    gemm_kernel<1><<<dim3(gemm_grid(6, NY)), b256, 0, stream>>>(
        gC, fc2T, p_fc2b, p_g2, buf0 + ro, 768, 3072, 6, NY);
  }

  tout_kernel<<<dim3(12, 56, 8), b256, 0, stream>>>(buf0, d_out, flag);
}